// Round 3
// baseline (590.942 us; speedup 1.0000x reference)
//
#include <hip/hip_runtime.h>
#include <hip/hip_bf16.h>
#include <cstdint>

// ---------------------------------------------------------------------------
// RoutesEncoder: gather+max over graph embedding, then 3x (Linear + ReLU).
// Established (rounds 0-2): ALL float tensors fp32 on device, output fp32,
// comparison done in bf16-rounded space (threshold 1.578e-2). idx int32/int64
// autodetected. Internal compute: bf16 MFMA with fp32 accumulation.
// ---------------------------------------------------------------------------

typedef __attribute__((ext_vector_type(8))) short          bf16x8; // MFMA A/B frag (4 VGPRs)
typedef __attribute__((ext_vector_type(8))) unsigned short u16x8;  // 16B vector store
typedef __attribute__((ext_vector_type(4))) float          f32x4;  // MFMA C/D frag

__device__ __forceinline__ unsigned short f2b_rne(float f) {
    union { float f; uint32_t i; } x; x.f = f;
    uint32_t lsb = (x.i >> 16) & 1u;
    return (unsigned short)((x.i + 0x7fffu + lsb) >> 16);
}

// ---------------------------------------------------------------------------
// Transpose-cast: W [K,N] fp32 row-major -> Wt [N,K] bf16 row-major (RNE).
// 32x32 tiles through LDS; pad 33 floats -> conflict-free transpose reads.
// ---------------------------------------------------------------------------
__global__ void transpose_f32_bf16(const float* __restrict__ W,
                                   unsigned short* __restrict__ Wt,
                                   int K, int N)
{
    __shared__ float tile[32][33];
    const int n0 = blockIdx.x * 32;
    const int k0 = blockIdx.y * 32;
    const int tx = threadIdx.x & 31;
    const int ty = threadIdx.x >> 5;   // 0..7
#pragma unroll
    for (int i = 0; i < 32; i += 8)
        tile[ty + i][tx] = W[(size_t)(k0 + ty + i) * N + (n0 + tx)];
    __syncthreads();
#pragma unroll
    for (int i = 0; i < 32; i += 8)
        Wt[(size_t)(n0 + ty + i) * K + (k0 + tx)] = f2b_rne(tile[tx][ty + i]);
}

// ---------------------------------------------------------------------------
// Gather + max over route positions.
// One wave per route: 64 lanes x 8 floats (two float4) = one 2KiB row / step.
// graph: [100000,512] fp32; idx: [n_routes,32] int32 OR int64 (autodetect);
// routes: [n_routes,512] bf16 (RNE).
// ---------------------------------------------------------------------------
__global__ void gather_max_kernel(const float* __restrict__ graph,
                                  const int* __restrict__ idx32,
                                  unsigned short* __restrict__ routes)
{
    // dtype autodetect (uniform across all waves): int64 iff the high dword
    // of each of the first 64 candidate int64 entries is zero (values <1e5).
    bool is64 = true;
#pragma unroll
    for (int k = 0; k < 64; k++) is64 &= (idx32[2 * k + 1] == 0);
    const int stride = is64 ? 64 : 32;   // int32 units per route
    const int step   = is64 ? 2  : 1;    // int32 units per entry

    const int wave  = threadIdx.x >> 6;          // 4 waves/block
    const int lane  = threadIdx.x & 63;
    const int route = blockIdx.x * 4 + wave;
    const int col   = lane * 8;                  // 8 floats per lane

    float m[8];
#pragma unroll
    for (int j = 0; j < 8; j++) m[j] = -INFINITY;

    const int* ip = idx32 + (size_t)route * stride;
#pragma unroll 4
    for (int l = 0; l < 32; l++) {
        const int node = ip[l * step];
        const float4* p = reinterpret_cast<const float4*>(graph + (size_t)node * 512 + col);
        float4 v0 = p[0];
        float4 v1 = p[1];
        m[0] = fmaxf(m[0], v0.x); m[1] = fmaxf(m[1], v0.y);
        m[2] = fmaxf(m[2], v0.z); m[3] = fmaxf(m[3], v0.w);
        m[4] = fmaxf(m[4], v1.x); m[5] = fmaxf(m[5], v1.y);
        m[6] = fmaxf(m[6], v1.z); m[7] = fmaxf(m[7], v1.w);
    }
    u16x8 o;
#pragma unroll
    for (int j = 0; j < 8; j++) o[j] = f2b_rne(m[j]);
    *reinterpret_cast<u16x8*>(routes + (size_t)route * 512 + col) = o;
}

// ---------------------------------------------------------------------------
// GEMM (B pre-transposed): C[M,N] = relu(A[M,K] * Bt[N,K]^T + bias[N])
// A,Bt bf16; bias fp32; C bf16 (intermediates) or fp32 (final output).
// 128x128 tile, BK=32, 256 thr = 4 waves (2x2), 64x64/wave via 4x4
// mfma_f32_16x16x32_bf16, fp32 accumulation.
// ---------------------------------------------------------------------------
#define BM 128
#define BN 128
#define BK 32
#define KPAD 8   // +16B per LDS row

template <typename OutT>
__global__ __launch_bounds__(256)
void gemm_bt_relu(const unsigned short* __restrict__ A,
                  const unsigned short* __restrict__ Bt,
                  const float* __restrict__ bias,
                  OutT* __restrict__ C,
                  int M, int N, int K)
{
    __shared__ unsigned short As[BM][BK + KPAD];
    __shared__ unsigned short Bs[BN][BK + KPAD];

    const int tid  = threadIdx.x;
    const int wave = tid >> 6;
    const int lane = tid & 63;
    const int quad = lane >> 4;
    const int l16  = lane & 15;
    const int wm   = (wave >> 1) * 64;   // wave M offset in tile
    const int wn   = (wave & 1) * 64;    // wave N offset in tile

    const int bm = blockIdx.y * BM;
    const int bn = blockIdx.x * BN;

    // staging: each thread loads 16 bf16 (32B) of A and of B per K-step
    const int sm = tid >> 1;             // tile row 0..127
    const int sk = (tid & 1) * 16;       // 0 or 16

    const unsigned short* Aptr = A  + (size_t)(bm + sm) * K + sk;
    const unsigned short* Bptr = Bt + (size_t)(bn + sm) * K + sk;

    f32x4 acc[4][4] = {};

    for (int k0 = 0; k0 < K; k0 += BK) {
        const uint4* ap = reinterpret_cast<const uint4*>(Aptr + k0);
        const uint4* bp = reinterpret_cast<const uint4*>(Bptr + k0);
        uint4 a0 = ap[0], a1 = ap[1];
        uint4 b0 = bp[0], b1 = bp[1];
        *reinterpret_cast<uint4*>(&As[sm][sk])     = a0;
        *reinterpret_cast<uint4*>(&As[sm][sk + 8]) = a1;
        *reinterpret_cast<uint4*>(&Bs[sm][sk])     = b0;
        *reinterpret_cast<uint4*>(&Bs[sm][sk + 8]) = b1;
        __syncthreads();

        bf16x8 a[4], b[4];
#pragma unroll
        for (int i = 0; i < 4; i++)
            a[i] = *reinterpret_cast<const bf16x8*>(&As[wm + i * 16 + l16][quad * 8]);
#pragma unroll
        for (int i = 0; i < 4; i++)
            b[i] = *reinterpret_cast<const bf16x8*>(&Bs[wn + i * 16 + l16][quad * 8]);

#pragma unroll
        for (int mi = 0; mi < 4; mi++)
#pragma unroll
            for (int ni = 0; ni < 4; ni++)
                acc[mi][ni] = __builtin_amdgcn_mfma_f32_16x16x32_bf16(
                    a[mi], b[ni], acc[mi][ni], 0, 0, 0);
        __syncthreads();
    }

    // epilogue: bias + relu + store
    // C/D layout: row = quad*4 + r, col = l16
#pragma unroll
    for (int ni = 0; ni < 4; ni++) {
        const int n  = bn + wn + ni * 16 + l16;
        const float bv = bias[n];
#pragma unroll
        for (int mi = 0; mi < 4; mi++) {
            const int mbase = bm + wm + mi * 16 + quad * 4;
#pragma unroll
            for (int r = 0; r < 4; r++) {
                float v = acc[mi][ni][r] + bv;
                v = fmaxf(v, 0.0f);
                if constexpr (sizeof(OutT) == 2)
                    C[(size_t)(mbase + r) * N + n] = (OutT)f2b_rne(v);
                else
                    C[(size_t)(mbase + r) * N + n] = (OutT)v;
            }
        }
    }
}

// ---------------------------------------------------------------------------
// Launch
// ---------------------------------------------------------------------------
extern "C" void kernel_launch(void* const* d_in, const int* in_sizes, int n_in,
                              void* d_out, int out_size, void* d_ws, size_t ws_size,
                              hipStream_t stream)
{
    constexpr int N_ROUTES = 16384;
    constexpr int D_GRAPH  = 512;
    constexpr int D_ROUTE  = 1024;

    const float* graph = (const float*)d_in[0];
    const int*   idx   = (const int*)d_in[1];
    const float* W0    = (const float*)d_in[2];
    const float* b0    = (const float*)d_in[3];
    const float* W1    = (const float*)d_in[4];
    const float* b1    = (const float*)d_in[5];
    const float* W2    = (const float*)d_in[6];
    const float* b2    = (const float*)d_in[7];
    float*       out   = (float*)d_out;          // fp32 output

    // workspace carve
    char* w = (char*)d_ws;
    unsigned short* Wt0    = (unsigned short*)w; w += (size_t)D_ROUTE * D_GRAPH * 2; // 1 MB
    unsigned short* Wt1    = (unsigned short*)w; w += (size_t)D_ROUTE * D_ROUTE * 2; // 2 MB
    unsigned short* Wt2    = (unsigned short*)w; w += (size_t)D_ROUTE * D_ROUTE * 2; // 2 MB
    unsigned short* routes = (unsigned short*)w; w += (size_t)N_ROUTES * D_GRAPH * 2; // 16 MB
    unsigned short* x1     = (unsigned short*)w; w += (size_t)N_ROUTES * D_ROUTE * 2; // 32 MB
    unsigned short* x2     = (unsigned short*)w; w += (size_t)N_ROUTES * D_ROUTE * 2; // 32 MB

    // 1) weight transpose-casts (fp32 [K,N] -> bf16 [N,K])
    transpose_f32_bf16<<<dim3(D_ROUTE / 32, D_GRAPH / 32), 256, 0, stream>>>(W0, Wt0, D_GRAPH, D_ROUTE);
    transpose_f32_bf16<<<dim3(D_ROUTE / 32, D_ROUTE / 32), 256, 0, stream>>>(W1, Wt1, D_ROUTE, D_ROUTE);
    transpose_f32_bf16<<<dim3(D_ROUTE / 32, D_ROUTE / 32), 256, 0, stream>>>(W2, Wt2, D_ROUTE, D_ROUTE);

    // 2) gather + max (one wave per route; idx width autodetected)
    gather_max_kernel<<<N_ROUTES / 4, 256, 0, stream>>>(graph, idx, routes);

    // 3) linear chain (bf16 MFMA, fp32 accum); intermediates bf16, final fp32
    gemm_bt_relu<unsigned short><<<dim3(D_ROUTE / BN, N_ROUTES / BM), 256, 0, stream>>>(
        routes, Wt0, b0, x1, N_ROUTES, D_ROUTE, D_GRAPH);
    gemm_bt_relu<unsigned short><<<dim3(D_ROUTE / BN, N_ROUTES / BM), 256, 0, stream>>>(
        x1, Wt1, b1, x2, N_ROUTES, D_ROUTE, D_ROUTE);
    gemm_bt_relu<float><<<dim3(D_ROUTE / BN, N_ROUTES / BM), 256, 0, stream>>>(
        x2, Wt2, b2, out, N_ROUTES, D_ROUTE, D_ROUTE);
}

// Round 4
// 570.403 us; speedup vs baseline: 1.0360x; 1.0360x over previous
//
#include <hip/hip_runtime.h>
#include <hip/hip_bf16.h>
#include <cstdint>

// ---------------------------------------------------------------------------
// RoutesEncoder: gather+max over graph embedding, then 3x (Linear + ReLU).
// Established: fp32 inputs, fp32 output, bf16-space comparison (thr 1.578e-2),
// idx int32/int64 autodetected. Internals: bf16 MFMA, fp32 accumulation.
// R4: GEMM staging via global_load_lds(16B) + swizzled LDS (conflict-free);
//     gather with 2 routes/wave for 2x memory-level parallelism.
// ---------------------------------------------------------------------------

typedef __attribute__((ext_vector_type(8))) short          bf16x8; // MFMA A/B frag
typedef __attribute__((ext_vector_type(8))) unsigned short u16x8;  // 16B vector store
typedef __attribute__((ext_vector_type(4))) float          f32x4;  // MFMA C/D frag

__device__ __forceinline__ unsigned short f2b_rne(float f) {
    union { float f; uint32_t i; } x; x.f = f;
    uint32_t lsb = (x.i >> 16) & 1u;
    return (unsigned short)((x.i + 0x7fffu + lsb) >> 16);
}

// async 16B global -> LDS (DMA; LDS dest must be wave-uniform base + lane*16)
__device__ __forceinline__ void async_copy16(const void* gptr, void* lptr) {
    __builtin_amdgcn_global_load_lds(
        (const __attribute__((address_space(1))) unsigned int*)gptr,
        (__attribute__((address_space(3))) unsigned int*)lptr, 16, 0, 0);
}

// ---------------------------------------------------------------------------
// Transpose-cast: W [K,N] fp32 row-major -> Wt [N,K] bf16 row-major (RNE).
// ---------------------------------------------------------------------------
__global__ void transpose_f32_bf16(const float* __restrict__ W,
                                   unsigned short* __restrict__ Wt,
                                   int K, int N)
{
    __shared__ float tile[32][33];
    const int n0 = blockIdx.x * 32;
    const int k0 = blockIdx.y * 32;
    const int tx = threadIdx.x & 31;
    const int ty = threadIdx.x >> 5;   // 0..7
#pragma unroll
    for (int i = 0; i < 32; i += 8)
        tile[ty + i][tx] = W[(size_t)(k0 + ty + i) * N + (n0 + tx)];
    __syncthreads();
#pragma unroll
    for (int i = 0; i < 32; i += 8)
        Wt[(size_t)(n0 + ty + i) * K + (k0 + tx)] = f2b_rne(tile[tx][ty + i]);
}

// ---------------------------------------------------------------------------
// Gather + max. One wave handles TWO routes (independent load chains -> 2x
// memory-level parallelism). 64 lanes x 8 floats = one 2KiB row per step.
// ---------------------------------------------------------------------------
__global__ void gather_max_kernel(const float* __restrict__ graph,
                                  const int* __restrict__ idx32,
                                  unsigned short* __restrict__ routes)
{
    // idx dtype autodetect (wave-uniform): int64 iff high dwords all zero.
    bool is64 = true;
#pragma unroll
    for (int k = 0; k < 64; k++) is64 &= (idx32[2 * k + 1] == 0);
    const int stride = is64 ? 64 : 32;   // int32 units per route
    const int step   = is64 ? 2  : 1;    // int32 units per entry

    const int wave  = threadIdx.x >> 6;
    const int lane  = threadIdx.x & 63;
    const int route = (blockIdx.x * 4 + wave) * 2;
    const int col   = lane * 8;

    float m0[8], m1[8];
#pragma unroll
    for (int j = 0; j < 8; j++) { m0[j] = -INFINITY; m1[j] = -INFINITY; }

    const int* ip0 = idx32 + (size_t)route * stride;
    const int* ip1 = ip0 + stride;
#pragma unroll 4
    for (int l = 0; l < 32; l++) {
        const int n0 = ip0[l * step];
        const int n1 = ip1[l * step];
        const float4* p0 = reinterpret_cast<const float4*>(graph + (size_t)n0 * 512 + col);
        const float4* p1 = reinterpret_cast<const float4*>(graph + (size_t)n1 * 512 + col);
        float4 a0 = p0[0], a1 = p0[1];
        float4 b0 = p1[0], b1 = p1[1];
        m0[0] = fmaxf(m0[0], a0.x); m0[1] = fmaxf(m0[1], a0.y);
        m0[2] = fmaxf(m0[2], a0.z); m0[3] = fmaxf(m0[3], a0.w);
        m0[4] = fmaxf(m0[4], a1.x); m0[5] = fmaxf(m0[5], a1.y);
        m0[6] = fmaxf(m0[6], a1.z); m0[7] = fmaxf(m0[7], a1.w);
        m1[0] = fmaxf(m1[0], b0.x); m1[1] = fmaxf(m1[1], b0.y);
        m1[2] = fmaxf(m1[2], b0.z); m1[3] = fmaxf(m1[3], b0.w);
        m1[4] = fmaxf(m1[4], b1.x); m1[5] = fmaxf(m1[5], b1.y);
        m1[6] = fmaxf(m1[6], b1.z); m1[7] = fmaxf(m1[7], b1.w);
    }
    u16x8 o0, o1;
#pragma unroll
    for (int j = 0; j < 8; j++) { o0[j] = f2b_rne(m0[j]); o1[j] = f2b_rne(m1[j]); }
    *reinterpret_cast<u16x8*>(routes + (size_t)route * 512 + col)       = o0;
    *reinterpret_cast<u16x8*>(routes + (size_t)(route + 1) * 512 + col) = o1;
}

// ---------------------------------------------------------------------------
// GEMM (B pre-transposed): C = relu(A[M,K] * Bt[N,K]^T + bias), bf16 in,
// fp32 accum. 128x128 tile, BK=32, 4 waves (2x2), 64x64/wave, 16x16x32 MFMA.
// Staging: global_load_lds 16B DMA. LDS 64B rows, NO padding; 16B chunk c of
// row r lives at chunk-position c ^ ((r>>1)&3)  ->  fragment ds_read_b128 is
// 2-way-per-bank (free), and staging source permutation stays inside each
// row's 64B line (coalescing unchanged).
// ---------------------------------------------------------------------------
#define BM 128
#define BN 128
#define BK 32

template <typename OutT>
__global__ __launch_bounds__(256)
void gemm_bt_relu(const unsigned short* __restrict__ A,
                  const unsigned short* __restrict__ Bt,
                  const float* __restrict__ bias,
                  OutT* __restrict__ C,
                  int M, int N, int K)
{
    __shared__ unsigned short As[BM * BK];   // 8 KB
    __shared__ unsigned short Bs[BN * BK];   // 8 KB

    const int tid  = threadIdx.x;
    const int wave = tid >> 6;
    const int lane = tid & 63;
    const int quad = lane >> 4;
    const int l16  = lane & 15;
    const int wm   = (wave >> 1) * 64;
    const int wn   = (wave & 1) * 64;

    const int bm = blockIdx.y * BM;
    const int bn = blockIdx.x * BN;

    // Each tile = 512 slots of 16B. Wave w, inst j covers slots [w*64+j*256, +64).
    // slot s: row = s>>2, chunkpos = s&3, source k-chunk c = chunkpos ^ ((row>>1)&3)
    const int s0 = wave * 64 + lane;
    const int s1 = s0 + 256;
    const int r0 = s0 >> 2, c0 = (s0 & 3) ^ ((r0 >> 1) & 3);
    const int r1 = s1 >> 2, c1 = (s1 & 3) ^ ((r1 >> 1) & 3);

    const unsigned short* a0g = A  + (size_t)(bm + r0) * K + c0 * 8;
    const unsigned short* a1g = A  + (size_t)(bm + r1) * K + c1 * 8;
    const unsigned short* b0g = Bt + (size_t)(bn + r0) * K + c0 * 8;
    const unsigned short* b1g = Bt + (size_t)(bn + r1) * K + c1 * 8;
    unsigned short* a0l = As + s0 * 8;
    unsigned short* a1l = As + s1 * 8;
    unsigned short* b0l = Bs + s0 * 8;
    unsigned short* b1l = Bs + s1 * 8;

    f32x4 acc[4][4] = {};

    for (int k0 = 0; k0 < K; k0 += BK) {
        async_copy16(a0g + k0, a0l);
        async_copy16(a1g + k0, a1l);
        async_copy16(b0g + k0, b0l);
        async_copy16(b1g + k0, b1l);
        __syncthreads();   // drains vmcnt (DMA) before LDS reads

        bf16x8 a[4], b[4];
#pragma unroll
        for (int i = 0; i < 4; i++) {
            const int row = wm + i * 16 + l16;
            const int cp  = quad ^ ((row >> 1) & 3);
            a[i] = *reinterpret_cast<const bf16x8*>(As + row * BK + cp * 8);
        }
#pragma unroll
        for (int i = 0; i < 4; i++) {
            const int row = wn + i * 16 + l16;
            const int cp  = quad ^ ((row >> 1) & 3);
            b[i] = *reinterpret_cast<const bf16x8*>(Bs + row * BK + cp * 8);
        }

#pragma unroll
        for (int mi = 0; mi < 4; mi++)
#pragma unroll
            for (int ni = 0; ni < 4; ni++)
                acc[mi][ni] = __builtin_amdgcn_mfma_f32_16x16x32_bf16(
                    a[mi], b[ni], acc[mi][ni], 0, 0, 0);
        __syncthreads();   // LDS reads done before next iter's DMA writes
    }

    // epilogue: bias + relu + store. C/D layout: row = quad*4 + r, col = l16
#pragma unroll
    for (int ni = 0; ni < 4; ni++) {
        const int n  = bn + wn + ni * 16 + l16;
        const float bv = bias[n];
#pragma unroll
        for (int mi = 0; mi < 4; mi++) {
            const int mbase = bm + wm + mi * 16 + quad * 4;
#pragma unroll
            for (int r = 0; r < 4; r++) {
                float v = acc[mi][ni][r] + bv;
                v = fmaxf(v, 0.0f);
                if constexpr (sizeof(OutT) == 2)
                    C[(size_t)(mbase + r) * N + n] = (OutT)f2b_rne(v);
                else
                    C[(size_t)(mbase + r) * N + n] = (OutT)v;
            }
        }
    }
}

// ---------------------------------------------------------------------------
// Launch
// ---------------------------------------------------------------------------
extern "C" void kernel_launch(void* const* d_in, const int* in_sizes, int n_in,
                              void* d_out, int out_size, void* d_ws, size_t ws_size,
                              hipStream_t stream)
{
    constexpr int N_ROUTES = 16384;
    constexpr int D_GRAPH  = 512;
    constexpr int D_ROUTE  = 1024;

    const float* graph = (const float*)d_in[0];
    const int*   idx   = (const int*)d_in[1];
    const float* W0    = (const float*)d_in[2];
    const float* b0    = (const float*)d_in[3];
    const float* W1    = (const float*)d_in[4];
    const float* b1    = (const float*)d_in[5];
    const float* W2    = (const float*)d_in[6];
    const float* b2    = (const float*)d_in[7];
    float*       out   = (float*)d_out;          // fp32 output

    // workspace carve
    char* w = (char*)d_ws;
    unsigned short* Wt0    = (unsigned short*)w; w += (size_t)D_ROUTE * D_GRAPH * 2;
    unsigned short* Wt1    = (unsigned short*)w; w += (size_t)D_ROUTE * D_ROUTE * 2;
    unsigned short* Wt2    = (unsigned short*)w; w += (size_t)D_ROUTE * D_ROUTE * 2;
    unsigned short* routes = (unsigned short*)w; w += (size_t)N_ROUTES * D_GRAPH * 2;
    unsigned short* x1     = (unsigned short*)w; w += (size_t)N_ROUTES * D_ROUTE * 2;
    unsigned short* x2     = (unsigned short*)w; w += (size_t)N_ROUTES * D_ROUTE * 2;

    // 1) weight transpose-casts (fp32 [K,N] -> bf16 [N,K])
    transpose_f32_bf16<<<dim3(D_ROUTE / 32, D_GRAPH / 32), 256, 0, stream>>>(W0, Wt0, D_GRAPH, D_ROUTE);
    transpose_f32_bf16<<<dim3(D_ROUTE / 32, D_ROUTE / 32), 256, 0, stream>>>(W1, Wt1, D_ROUTE, D_ROUTE);
    transpose_f32_bf16<<<dim3(D_ROUTE / 32, D_ROUTE / 32), 256, 0, stream>>>(W2, Wt2, D_ROUTE, D_ROUTE);

    // 2) gather + max (2 routes per wave)
    gather_max_kernel<<<N_ROUTES / 8, 256, 0, stream>>>(graph, idx, routes);

    // 3) linear chain (bf16 MFMA, fp32 accum); intermediates bf16, final fp32
    gemm_bt_relu<unsigned short><<<dim3(D_ROUTE / BN, N_ROUTES / BM), 256, 0, stream>>>(
        routes, Wt0, b0, x1, N_ROUTES, D_ROUTE, D_GRAPH);
    gemm_bt_relu<unsigned short><<<dim3(D_ROUTE / BN, N_ROUTES / BM), 256, 0, stream>>>(
        x1, Wt1, b1, x2, N_ROUTES, D_ROUTE, D_ROUTE);
    gemm_bt_relu<float><<<dim3(D_ROUTE / BN, N_ROUTES / BM), 256, 0, stream>>>(
        x2, Wt2, b2, out, N_ROUTES, D_ROUTE, D_ROUTE);
}

// Round 5
// 539.896 us; speedup vs baseline: 1.0945x; 1.0565x over previous
//
#include <hip/hip_runtime.h>
#include <hip/hip_bf16.h>
#include <cstdint>

// ---------------------------------------------------------------------------
// RoutesEncoder: gather+max over graph embedding, then 3x (Linear + ReLU).
// Established: fp32 inputs, fp32 output, bf16-space comparison (thr 1.578e-2),
// idx int32/int64 autodetected. Internals: bf16 MFMA, fp32 accumulation.
// R5: (a) pre-convert graph table to bf16 (halves gather bytes; exact since
//     RNE is monotone => max(rne(x)) == rne(max(x))), 4 routes/wave gather;
//     (b) GEMM BK=64, compile-time shapes, XOR-swizzled LDS + 16B DMA staging.
// ---------------------------------------------------------------------------

typedef __attribute__((ext_vector_type(8))) short          bf16x8; // MFMA A/B frag
typedef __attribute__((ext_vector_type(8))) unsigned short u16x8;  // 16B vector ld/st
typedef __attribute__((ext_vector_type(4))) float          f32x4;  // MFMA C/D frag

__device__ __forceinline__ unsigned short f2b_rne(float f) {
    union { float f; uint32_t i; } x; x.f = f;
    uint32_t lsb = (x.i >> 16) & 1u;
    return (unsigned short)((x.i + 0x7fffu + lsb) >> 16);
}
__device__ __forceinline__ float b2f(unsigned short u) {
    union { float f; uint32_t i; } x; x.i = ((uint32_t)u) << 16; return x.f;
}

// async 16B global->LDS DMA. HW scatters lane i to ldsbase + i*16; our lptr is
// exactly base + lane*16 in wave-lane order (contract verified rounds 4).
__device__ __forceinline__ void async_copy16(const void* gptr, void* lptr) {
    __builtin_amdgcn_global_load_lds(
        (const __attribute__((address_space(1))) unsigned int*)gptr,
        (__attribute__((address_space(3))) unsigned int*)lptr, 16, 0, 0);
}

// ---------------------------------------------------------------------------
// Streaming cast: graph fp32 -> bf16 (RNE). 8 floats/thread.
// ---------------------------------------------------------------------------
__global__ __launch_bounds__(256)
void convert_f32_bf16(const float* __restrict__ in, unsigned short* __restrict__ out)
{
    const size_t i = ((size_t)blockIdx.x * 256 + threadIdx.x) * 8;
    const float4* p = reinterpret_cast<const float4*>(in + i);
    float4 v0 = p[0], v1 = p[1];
    u16x8 o;
    o[0] = f2b_rne(v0.x); o[1] = f2b_rne(v0.y); o[2] = f2b_rne(v0.z); o[3] = f2b_rne(v0.w);
    o[4] = f2b_rne(v1.x); o[5] = f2b_rne(v1.y); o[6] = f2b_rne(v1.z); o[7] = f2b_rne(v1.w);
    *reinterpret_cast<u16x8*>(out + i) = o;
}

// ---------------------------------------------------------------------------
// Transpose-cast: W [K,N] fp32 -> Wt [N,K] bf16 (RNE).
// ---------------------------------------------------------------------------
__global__ void transpose_f32_bf16(const float* __restrict__ W,
                                   unsigned short* __restrict__ Wt,
                                   int K, int N)
{
    __shared__ float tile[32][33];
    const int n0 = blockIdx.x * 32;
    const int k0 = blockIdx.y * 32;
    const int tx = threadIdx.x & 31;
    const int ty = threadIdx.x >> 5;
#pragma unroll
    for (int i = 0; i < 32; i += 8)
        tile[ty + i][tx] = W[(size_t)(k0 + ty + i) * N + (n0 + tx)];
    __syncthreads();
#pragma unroll
    for (int i = 0; i < 32; i += 8)
        Wt[(size_t)(n0 + ty + i) * K + (k0 + tx)] = f2b_rne(tile[tx][ty + i]);
}

// ---------------------------------------------------------------------------
// Gather+max from BF16 table: one wave handles FOUR routes (4 independent
// load chains). Row = 1KB = 64 lanes x 16B -> one load per row.
// ---------------------------------------------------------------------------
__global__ void gather_max_bf16(const unsigned short* __restrict__ graphb,
                                const int* __restrict__ idx32,
                                unsigned short* __restrict__ routes)
{
    bool is64 = true;
#pragma unroll
    for (int k = 0; k < 64; k++) is64 &= (idx32[2 * k + 1] == 0);
    const int stride = is64 ? 64 : 32;
    const int step   = is64 ? 2  : 1;

    const int wave  = threadIdx.x >> 6;
    const int lane  = threadIdx.x & 63;
    const int route = (blockIdx.x * 4 + wave) * 4;
    const int col   = lane * 8;                 // 8 bf16 = 16B per lane

    float m[4][8];
#pragma unroll
    for (int t = 0; t < 4; t++)
#pragma unroll
        for (int j = 0; j < 8; j++) m[t][j] = -INFINITY;

    const int* ip = idx32 + (size_t)route * stride;
#pragma unroll 2
    for (int l = 0; l < 32; l++) {
        u16x8 v[4];
#pragma unroll
        for (int t = 0; t < 4; t++) {
            const int node = ip[t * stride + l * step];
            v[t] = *reinterpret_cast<const u16x8*>(graphb + (size_t)node * 512 + col);
        }
#pragma unroll
        for (int t = 0; t < 4; t++)
#pragma unroll
            for (int j = 0; j < 8; j++)
                m[t][j] = fmaxf(m[t][j], b2f(v[t][j]));
    }
#pragma unroll
    for (int t = 0; t < 4; t++) {
        u16x8 o;
#pragma unroll
        for (int j = 0; j < 8; j++) {
            union { float f; uint32_t i; } x; x.f = m[t][j];
            o[j] = (unsigned short)(x.i >> 16);   // exact: max of bf16s is a bf16
        }
        *reinterpret_cast<u16x8*>(routes + (size_t)(route + t) * 512 + col) = o;
    }
}

// fp32-table fallback (round-4 version, 2 routes/wave) if ws can't hold graphb
__global__ void gather_max_f32(const float* __restrict__ graph,
                               const int* __restrict__ idx32,
                               unsigned short* __restrict__ routes)
{
    bool is64 = true;
#pragma unroll
    for (int k = 0; k < 64; k++) is64 &= (idx32[2 * k + 1] == 0);
    const int stride = is64 ? 64 : 32;
    const int step   = is64 ? 2  : 1;

    const int wave  = threadIdx.x >> 6;
    const int lane  = threadIdx.x & 63;
    const int route = (blockIdx.x * 4 + wave) * 2;
    const int col   = lane * 8;

    float m0[8], m1[8];
#pragma unroll
    for (int j = 0; j < 8; j++) { m0[j] = -INFINITY; m1[j] = -INFINITY; }

    const int* ip0 = idx32 + (size_t)route * stride;
    const int* ip1 = ip0 + stride;
#pragma unroll 4
    for (int l = 0; l < 32; l++) {
        const int n0 = ip0[l * step];
        const int n1 = ip1[l * step];
        const float4* p0 = reinterpret_cast<const float4*>(graph + (size_t)n0 * 512 + col);
        const float4* p1 = reinterpret_cast<const float4*>(graph + (size_t)n1 * 512 + col);
        float4 a0 = p0[0], a1 = p0[1];
        float4 b0 = p1[0], b1 = p1[1];
        m0[0] = fmaxf(m0[0], a0.x); m0[1] = fmaxf(m0[1], a0.y);
        m0[2] = fmaxf(m0[2], a0.z); m0[3] = fmaxf(m0[3], a0.w);
        m0[4] = fmaxf(m0[4], a1.x); m0[5] = fmaxf(m0[5], a1.y);
        m0[6] = fmaxf(m0[6], a1.z); m0[7] = fmaxf(m0[7], a1.w);
        m1[0] = fmaxf(m1[0], b0.x); m1[1] = fmaxf(m1[1], b0.y);
        m1[2] = fmaxf(m1[2], b0.z); m1[3] = fmaxf(m1[3], b0.w);
        m1[4] = fmaxf(m1[4], b1.x); m1[5] = fmaxf(m1[5], b1.y);
        m1[6] = fmaxf(m1[6], b1.z); m1[7] = fmaxf(m1[7], b1.w);
    }
    u16x8 o0, o1;
#pragma unroll
    for (int j = 0; j < 8; j++) { o0[j] = f2b_rne(m0[j]); o1[j] = f2b_rne(m1[j]); }
    *reinterpret_cast<u16x8*>(routes + (size_t)route * 512 + col)       = o0;
    *reinterpret_cast<u16x8*>(routes + (size_t)(route + 1) * 512 + col) = o1;
}

// ---------------------------------------------------------------------------
// GEMM (B^T): C = relu(A[M,K]*Bt[N,K]^T + bias). bf16 in, fp32 accum.
// 128x128 tile, BK=64, 4 waves (2x2), 64x64/wave, 16x16x32 MFMA (2 k-steps
// per LDS tile => 32 MFMA per barrier pair). Staging: global_load_lds 16B.
// LDS rows 128B unpadded; chunk c of row r stored at position c ^ (r&7):
// fragment reads hit all 8 bank-quads with 2 lanes each (2-way = free).
// ---------------------------------------------------------------------------
template <int K, typename OutT>
__global__ __launch_bounds__(256)
void gemm_bt_relu(const unsigned short* __restrict__ A,
                  const unsigned short* __restrict__ Bt,
                  const float* __restrict__ bias,
                  OutT* __restrict__ C)
{
    constexpr int N  = 1024;
    constexpr int BK = 64;      // k per LDS tile
    __shared__ unsigned short As[128 * BK];   // 16 KB
    __shared__ unsigned short Bs[128 * BK];   // 16 KB

    const int tid  = threadIdx.x;
    const int wave = tid >> 6;
    const int lane = tid & 63;
    const int quad = lane >> 4;
    const int l16  = lane & 15;
    const int wm   = (wave >> 1) * 64;
    const int wn   = (wave & 1) * 64;

    const int bm = blockIdx.y * 128;
    const int bn = blockIdx.x * 128;

    // staging slots: 128 rows x 8 chunks(16B) = 1024 slots; 4 per thread.
    int sr[4], sc[4];
    const unsigned short *ag[4], *bg[4];
    unsigned short *al[4], *bl[4];
#pragma unroll
    for (int j = 0; j < 4; j++) {
        const int s = wave * 64 + lane + j * 256;
        const int r = s >> 3;
        const int c = (s & 7) ^ (r & 7);        // source chunk for this slot
        sr[j] = r; sc[j] = c;
        ag[j] = A  + (size_t)(bm + r) * K + c * 8;
        bg[j] = Bt + (size_t)(bn + r) * K + c * 8;
        al[j] = As + s * 8;
        bl[j] = Bs + s * 8;
    }

    f32x4 acc[4][4] = {};

    for (int k0 = 0; k0 < K; k0 += BK) {
#pragma unroll
        for (int j = 0; j < 4; j++) async_copy16(ag[j] + k0, al[j]);
#pragma unroll
        for (int j = 0; j < 4; j++) async_copy16(bg[j] + k0, bl[j]);
        __syncthreads();   // drains DMA (vmcnt) before LDS reads

#pragma unroll
        for (int kk = 0; kk < 2; kk++) {
            const int ch = kk * 4 + quad;       // logical chunk for this frag
            bf16x8 a[4], b[4];
#pragma unroll
            for (int i = 0; i < 4; i++) {
                const int row = wm + i * 16 + l16;
                a[i] = *reinterpret_cast<const bf16x8*>(
                    As + row * BK + (ch ^ (row & 7)) * 8);
            }
#pragma unroll
            for (int i = 0; i < 4; i++) {
                const int row = wn + i * 16 + l16;
                b[i] = *reinterpret_cast<const bf16x8*>(
                    Bs + row * BK + (ch ^ (row & 7)) * 8);
            }
#pragma unroll
            for (int mi = 0; mi < 4; mi++)
#pragma unroll
                for (int ni = 0; ni < 4; ni++)
                    acc[mi][ni] = __builtin_amdgcn_mfma_f32_16x16x32_bf16(
                        a[mi], b[ni], acc[mi][ni], 0, 0, 0);
        }
        __syncthreads();
    }

    // epilogue: bias + relu + store. C/D layout: row = quad*4 + r, col = l16
#pragma unroll
    for (int ni = 0; ni < 4; ni++) {
        const int n  = bn + wn + ni * 16 + l16;
        const float bv = bias[n];
#pragma unroll
        for (int mi = 0; mi < 4; mi++) {
            const int mbase = bm + wm + mi * 16 + quad * 4;
#pragma unroll
            for (int r = 0; r < 4; r++) {
                float v = acc[mi][ni][r] + bv;
                v = fmaxf(v, 0.0f);
                if constexpr (sizeof(OutT) == 2)
                    C[(size_t)(mbase + r) * N + n] = (OutT)f2b_rne(v);
                else
                    C[(size_t)(mbase + r) * N + n] = (OutT)v;
            }
        }
    }
}

// ---------------------------------------------------------------------------
// Launch
// ---------------------------------------------------------------------------
extern "C" void kernel_launch(void* const* d_in, const int* in_sizes, int n_in,
                              void* d_out, int out_size, void* d_ws, size_t ws_size,
                              hipStream_t stream)
{
    constexpr int N_ROUTES = 16384;
    constexpr int N_NODES  = 100000;
    constexpr int D_GRAPH  = 512;
    constexpr int D_ROUTE  = 1024;

    const float* graph = (const float*)d_in[0];
    const int*   idx   = (const int*)d_in[1];
    const float* W0    = (const float*)d_in[2];
    const float* b0    = (const float*)d_in[3];
    const float* W1    = (const float*)d_in[4];
    const float* b1    = (const float*)d_in[5];
    const float* W2    = (const float*)d_in[6];
    const float* b2    = (const float*)d_in[7];
    float*       out   = (float*)d_out;

    // workspace carve
    char* w = (char*)d_ws;
    unsigned short* Wt0    = (unsigned short*)w; w += (size_t)D_ROUTE * D_GRAPH * 2;  // 1 MB
    unsigned short* Wt1    = (unsigned short*)w; w += (size_t)D_ROUTE * D_ROUTE * 2;  // 2 MB
    unsigned short* Wt2    = (unsigned short*)w; w += (size_t)D_ROUTE * D_ROUTE * 2;  // 2 MB
    unsigned short* routes = (unsigned short*)w; w += (size_t)N_ROUTES * D_GRAPH * 2; // 16 MB
    unsigned short* x1     = (unsigned short*)w; w += (size_t)N_ROUTES * D_ROUTE * 2; // 32 MB
    unsigned short* x2     = (unsigned short*)w; w += (size_t)N_ROUTES * D_ROUTE * 2; // 32 MB
    unsigned short* graphb = (unsigned short*)w;
    const size_t need_bf16 = (size_t)(w - (char*)d_ws) + (size_t)N_NODES * D_GRAPH * 2;
    const bool   use_bf16  = (ws_size >= need_bf16);

    // 1) weight transpose-casts (fp32 [K,N] -> bf16 [N,K])
    transpose_f32_bf16<<<dim3(D_ROUTE / 32, D_GRAPH / 32), 256, 0, stream>>>(W0, Wt0, D_GRAPH, D_ROUTE);
    transpose_f32_bf16<<<dim3(D_ROUTE / 32, D_ROUTE / 32), 256, 0, stream>>>(W1, Wt1, D_ROUTE, D_ROUTE);
    transpose_f32_bf16<<<dim3(D_ROUTE / 32, D_ROUTE / 32), 256, 0, stream>>>(W2, Wt2, D_ROUTE, D_ROUTE);

    // 2) gather + max
    if (use_bf16) {
        // cast table to bf16 (51.2M elems / 8 per thread = 6.4M threads)
        convert_f32_bf16<<<(N_NODES * D_GRAPH / 8) / 256, 256, 0, stream>>>(graph, graphb);
        gather_max_bf16<<<N_ROUTES / 16, 256, 0, stream>>>(graphb, idx, routes);
    } else {
        gather_max_f32<<<N_ROUTES / 8, 256, 0, stream>>>(graph, idx, routes);
    }

    // 3) linear chain (bf16 MFMA, fp32 accum); intermediates bf16, final fp32
    gemm_bt_relu<512,  unsigned short><<<dim3(D_ROUTE / 128, N_ROUTES / 128), 256, 0, stream>>>(
        routes, Wt0, b0, x1);
    gemm_bt_relu<1024, unsigned short><<<dim3(D_ROUTE / 128, N_ROUTES / 128), 256, 0, stream>>>(
        x1, Wt1, b1, x2);
    gemm_bt_relu<1024, float><<<dim3(D_ROUTE / 128, N_ROUTES / 128), 256, 0, stream>>>(
        x2, Wt2, b2, out);
}